// Round 8
// baseline (228.317 us; speedup 1.0000x reference)
//
#include <hip/hip_runtime.h>

#define N 8192
#define DIM 64

typedef float f32x4 __attribute__((ext_vector_type(4)));
typedef short bf16x8 __attribute__((ext_vector_type(8)));

__device__ __forceinline__ unsigned short f32_to_bf16_rne(float f) {
  unsigned int u = __float_as_uint(f);
  unsigned int r = (u + 0x7FFFu + ((u >> 16) & 1u)) >> 16;
  return (unsigned short)r;
}

// x (f32 [N][64]) -> xb (bf16 [N][64]); block 0 also zeroes the 128 row-group
// counters (safe: counters are only read by main_kernel, which runs after).
__global__ void cvt_kernel(const float* __restrict__ x, unsigned short* __restrict__ xb,
                           int* __restrict__ cnt) {
  int gid = blockIdx.x * blockDim.x + threadIdx.x;
  if (blockIdx.x == 0 && threadIdx.x < 128) cnt[threadIdx.x] = 0;
  float4 v = reinterpret_cast<const float4*>(x)[gid];
  ushort4 o;
  o.x = f32_to_bf16_rne(v.x);
  o.y = f32_to_bf16_rne(v.y);
  o.z = f32_to_bf16_rne(v.z);
  o.w = f32_to_bf16_rne(v.w);
  reinterpret_cast<ushort4*>(xb)[gid] = o;
}

// Grid: 1024 blocks = 128 row-groups x 8 j-chunks, 256 threads (4 waves).
// XCD-aware swizzle (T1). Swapped-Gram MFMA; A float4 loads (R1 structure).
// FUSED FINISH: the 8 blocks of a row-group rendezvous on cnt[rg]; the 8th
// arrival computes out[] for rows [rg*64, rg*64+64) summing the 8 spart
// slices in fixed js order (bit-deterministic), then resets cnt[rg] to 0
// (self-cleaning for graph replays).
__global__ __launch_bounds__(256, 4) void main_kernel(
    const float* __restrict__ A,
    const unsigned short* __restrict__ xb,
    const float* __restrict__ x,
    float* __restrict__ spart,
    int* __restrict__ cnt,
    float* __restrict__ out) {
  int bid = blockIdx.x;
  int xcd = bid & 7;
  int slot = bid >> 3;               // 0..127 within XCD
  int rg = xcd * 16 + (slot & 15);   // contiguous 16 row-groups per XCD
  int js = slot >> 4;                // 0..7
  int tid = threadIdx.x;
  int w = tid >> 6;
  int lane = tid & 63;
  int i0 = rg * 64;
  int jbase = js * 1024 + w * 256;
  int c = lane & 15;   // operand row/col selector, D column (i)
  int q = lane >> 4;   // k-quad; D row group (j)

  // B-operand fragments (i-side), persistent: B[k][col=c] = X[i0+it*16+c][k]
  bf16x8 xi[4][2];
#pragma unroll
  for (int it = 0; it < 4; ++it)
#pragma unroll
    for (int kb = 0; kb < 2; ++kb)
      xi[it][kb] = *reinterpret_cast<const bf16x8*>(
          xb + (size_t)(i0 + it * 16 + c) * DIM + kb * 32 + q * 8);

  // Per-it A row pointer: row i0+it*16+c, col jbase + q*4 (+ jt*16 folds to imm)
  const float* pA[4];
#pragma unroll
  for (int it = 0; it < 4; ++it)
    pA[it] = A + (size_t)(i0 + it * 16 + c) * N + jbase + q * 4;

  float sacc[4] = {0.f, 0.f, 0.f, 0.f};

  f32x4 a_buf[2][4];
  bf16x8 xj_buf[2][2];

  // prologue: jt=0 loads
#pragma unroll
  for (int it = 0; it < 4; ++it)
    a_buf[0][it] = *reinterpret_cast<const f32x4*>(pA[it]);
  {
    const unsigned short* pj = xb + (size_t)(jbase + c) * DIM + q * 8;
    xj_buf[0][0] = *reinterpret_cast<const bf16x8*>(pj);
    xj_buf[0][1] = *reinterpret_cast<const bf16x8*>(pj + 32);
  }

#pragma unroll
  for (int jt = 0; jt < 16; ++jt) {
    const int cur = jt & 1, nxt = cur ^ 1;
    if (jt < 15) {
#pragma unroll
      for (int it = 0; it < 4; ++it)
        a_buf[nxt][it] =
            *reinterpret_cast<const f32x4*>(pA[it] + (jt + 1) * 16);
      const unsigned short* pj =
          xb + (size_t)(jbase + (jt + 1) * 16 + c) * DIM + q * 8;
      xj_buf[nxt][0] = *reinterpret_cast<const bf16x8*>(pj);
      xj_buf[nxt][1] = *reinterpret_cast<const bf16x8*>(pj + 32);
    }
#pragma unroll
    for (int it = 0; it < 4; ++it) {
      f32x4 g = {0.f, 0.f, 0.f, 0.f};
      g = __builtin_amdgcn_mfma_f32_16x16x32_bf16(xj_buf[cur][0], xi[it][0], g, 0, 0, 0);
      g = __builtin_amdgcn_mfma_f32_16x16x32_bf16(xj_buf[cur][1], xi[it][1], g, 0, 0, 0);
      f32x4 a4 = a_buf[cur][it];
      sacc[it] = fmaf(a4[0], g[0], sacc[it]);
      sacc[it] = fmaf(a4[1], g[1], sacc[it]);
      sacc[it] = fmaf(a4[2], g[2], sacc[it]);
      sacc[it] = fmaf(a4[3], g[3], sacc[it]);
    }
  }

  // Sum over q (j sub-blocks within the wave): lanes c, c+16, c+32, c+48
#pragma unroll
  for (int it = 0; it < 4; ++it) {
    float s = sacc[it];
    s += __shfl_xor(s, 16);
    s += __shfl_xor(s, 32);
    sacc[it] = s;
  }

  __shared__ float red[4][64];
  __shared__ int arrival;
  if (q == 0) {
#pragma unroll
    for (int it = 0; it < 4; ++it)
      red[w][it * 16 + c] = sacc[it];
  }
  __syncthreads();
  if (tid < 64) {
    float s = red[0][tid] + red[1][tid] + red[2][tid] + red[3][tid];
    spart[(size_t)js * N + i0 + tid] = s;
  }

  // ---- rendezvous: 8th block of this row-group runs the finish ----
  __threadfence();  // make spart writes visible device-wide before signaling
  if (tid == 0) arrival = atomicAdd(&cnt[rg], 1);
  __syncthreads();
  if (arrival != 7) return;
  __threadfence();  // acquire: order spart reads after observing all arrivals

  // finish rows [i0, i0+64): thread t -> row r=t>>2, dim quad (t&3)*16..+15
  int r = tid >> 2, qd = tid & 3;
  int i = i0 + r;
  float s = 0.f;
#pragma unroll
  for (int cc = 0; cc < 8; ++cc) s += spart[(size_t)cc * N + i];  // fixed order
  const float* xrow = x + (size_t)i * DIM + qd * 16;
  float* orow = out + (size_t)i * DIM + qd * 16;
#pragma unroll
  for (int m = 0; m < 4; ++m) {
    f32x4 xv = *reinterpret_cast<const f32x4*>(xrow + m * 4);
    f32x4 o;
    o[0] = 1.0f - 0.1f * xv[0] - 0.01f * s;
    o[1] = 1.0f - 0.1f * xv[1] - 0.01f * s;
    o[2] = 1.0f - 0.1f * xv[2] - 0.01f * s;
    o[3] = 1.0f - 0.1f * xv[3] - 0.01f * s;
    *reinterpret_cast<f32x4*>(orow + m * 4) = o;
  }

  // self-clean for next graph replay (ws is not re-poisoned between replays)
  if (tid == 0) atomicExch(&cnt[rg], 0);
}

extern "C" void kernel_launch(void* const* d_in, const int* in_sizes, int n_in,
                              void* d_out, int out_size, void* d_ws, size_t ws_size,
                              hipStream_t stream) {
  // d_in[0] = t (unused), d_in[1] = x f32 [8192][64], d_in[2] = A f32 [8192][8192]
  const float* x = (const float*)d_in[1];
  const float* A = (const float*)d_in[2];
  float* out = (float*)d_out;

  unsigned short* xb = (unsigned short*)d_ws;                  // 1 MB bf16 x
  float* spart = (float*)((char*)d_ws + (size_t)N * DIM * 2);  // 256 KB partials [8][8192]
  int* cnt = (int*)((char*)d_ws + (size_t)N * DIM * 2 + (size_t)8 * N * 4);  // 128 counters

  cvt_kernel<<<512, 256, 0, stream>>>(x, xb, cnt);
  main_kernel<<<1024, 256, 0, stream>>>(A, xb, x, spart, cnt, out);
}

// Round 9
// 74.189 us; speedup vs baseline: 3.0775x; 3.0775x over previous
//
#include <hip/hip_runtime.h>

#define N 8192
#define DIM 64

typedef float f32x4 __attribute__((ext_vector_type(4)));
typedef short bf16x8 __attribute__((ext_vector_type(8)));

__device__ __forceinline__ unsigned short f32_to_bf16_rne(float f) {
  unsigned int u = __float_as_uint(f);
  unsigned int r = (u + 0x7FFFu + ((u >> 16) & 1u)) >> 16;
  return (unsigned short)r;
}

// x (f32 [N][64]) -> xb (bf16 [N][64]); 131072 threads, 4 elems each
__global__ void cvt_kernel(const float* __restrict__ x, unsigned short* __restrict__ xb) {
  int gid = blockIdx.x * blockDim.x + threadIdx.x;
  float4 v = reinterpret_cast<const float4*>(x)[gid];
  ushort4 o;
  o.x = f32_to_bf16_rne(v.x);
  o.y = f32_to_bf16_rne(v.y);
  o.z = f32_to_bf16_rne(v.z);
  o.w = f32_to_bf16_rne(v.w);
  reinterpret_cast<ushort4*>(xb)[gid] = o;
}

// Grid: 1024 blocks = 128 row-groups x 8 j-chunks, 256 threads (4 waves).
// XCD-aware swizzle (T1): XCD x (= bid%8) owns contiguous A row-stripe.
// Swapped-Gram: D[j'][i'] = mfma(xj_frag, xi_frag); lane (q,c) holds
// G[jt*16+q*4+v][i0+it*16+c] -> A loads are contiguous float4 along j.
// NOTE (R7 lesson): no device-scope fences/atomics anywhere — agent-scope
// fence forces per-XCD L2 writeback/invalidate, ~+150us chip-wide stall.
__global__ __launch_bounds__(256, 4) void main_kernel(
    const float* __restrict__ A,
    const unsigned short* __restrict__ xb,
    float* __restrict__ spart) {
  int bid = blockIdx.x;
  int xcd = bid & 7;
  int slot = bid >> 3;               // 0..127 within XCD
  int rg = xcd * 16 + (slot & 15);   // contiguous 16 row-groups per XCD
  int js = slot >> 4;                // 0..7
  int tid = threadIdx.x;
  int w = tid >> 6;
  int lane = tid & 63;
  int i0 = rg * 64;
  int jbase = js * 1024 + w * 256;
  int c = lane & 15;   // operand row/col selector, D column (i)
  int q = lane >> 4;   // k-quad; D row group (j)

  // B-operand fragments (i-side), persistent: B[k][col=c] = X[i0+it*16+c][k]
  bf16x8 xi[4][2];
#pragma unroll
  for (int it = 0; it < 4; ++it)
#pragma unroll
    for (int kb = 0; kb < 2; ++kb)
      xi[it][kb] = *reinterpret_cast<const bf16x8*>(
          xb + (size_t)(i0 + it * 16 + c) * DIM + kb * 32 + q * 8);

  // Per-it A row pointer: row i0+it*16+c, col jbase + q*4 (+ jt*16 folds to imm)
  const float* pA[4];
#pragma unroll
  for (int it = 0; it < 4; ++it)
    pA[it] = A + (size_t)(i0 + it * 16 + c) * N + jbase + q * 4;

  float sacc[4] = {0.f, 0.f, 0.f, 0.f};

  f32x4 a_buf[2][4];
  bf16x8 xj_buf[2][2];

  // prologue: jt=0 loads
#pragma unroll
  for (int it = 0; it < 4; ++it)
    a_buf[0][it] = *reinterpret_cast<const f32x4*>(pA[it]);
  {
    const unsigned short* pj = xb + (size_t)(jbase + c) * DIM + q * 8;
    xj_buf[0][0] = *reinterpret_cast<const bf16x8*>(pj);
    xj_buf[0][1] = *reinterpret_cast<const bf16x8*>(pj + 32);
  }

#pragma unroll
  for (int jt = 0; jt < 16; ++jt) {
    const int cur = jt & 1, nxt = cur ^ 1;
    if (jt < 15) {
#pragma unroll
      for (int it = 0; it < 4; ++it)
        a_buf[nxt][it] =
            *reinterpret_cast<const f32x4*>(pA[it] + (jt + 1) * 16);
      const unsigned short* pj =
          xb + (size_t)(jbase + (jt + 1) * 16 + c) * DIM + q * 8;
      xj_buf[nxt][0] = *reinterpret_cast<const bf16x8*>(pj);
      xj_buf[nxt][1] = *reinterpret_cast<const bf16x8*>(pj + 32);
    }
#pragma unroll
    for (int it = 0; it < 4; ++it) {
      f32x4 g = {0.f, 0.f, 0.f, 0.f};
      g = __builtin_amdgcn_mfma_f32_16x16x32_bf16(xj_buf[cur][0], xi[it][0], g, 0, 0, 0);
      g = __builtin_amdgcn_mfma_f32_16x16x32_bf16(xj_buf[cur][1], xi[it][1], g, 0, 0, 0);
      f32x4 a4 = a_buf[cur][it];
      sacc[it] = fmaf(a4[0], g[0], sacc[it]);
      sacc[it] = fmaf(a4[1], g[1], sacc[it]);
      sacc[it] = fmaf(a4[2], g[2], sacc[it]);
      sacc[it] = fmaf(a4[3], g[3], sacc[it]);
    }
  }

  // Sum over q (j sub-blocks within the wave): lanes c, c+16, c+32, c+48
#pragma unroll
  for (int it = 0; it < 4; ++it) {
    float s = sacc[it];
    s += __shfl_xor(s, 16);
    s += __shfl_xor(s, 32);
    sacc[it] = s;
  }

  __shared__ float red[4][64];
  if (q == 0) {
#pragma unroll
    for (int it = 0; it < 4; ++it)
      red[w][it * 16 + c] = sacc[it];
  }
  __syncthreads();
  if (tid < 64) {
    float s = red[0][tid] + red[1][tid] + red[2][tid] + red[3][tid];
    spart[(size_t)js * N + i0 + tid] = s;
  }
}

// out[i][d] = 1 - 0.1*x[i][d] - 0.01*sum_c spart[c][i]; 131072 threads, 4 elems each
__global__ void finish_kernel(const float* __restrict__ x,
                              const float* __restrict__ spart,
                              float* __restrict__ out) {
  int gid = blockIdx.x * blockDim.x + threadIdx.x;
  float4 xv = reinterpret_cast<const float4*>(x)[gid];
  int i = gid >> 4;  // (gid*4)/64
  float s = 0.f;
#pragma unroll
  for (int cc = 0; cc < 8; ++cc) s += spart[(size_t)cc * N + i];
  float4 o;
  o.x = 1.0f - 0.1f * xv.x - 0.01f * s;
  o.y = 1.0f - 0.1f * xv.y - 0.01f * s;
  o.z = 1.0f - 0.1f * xv.z - 0.01f * s;
  o.w = 1.0f - 0.1f * xv.w - 0.01f * s;
  reinterpret_cast<float4*>(out)[gid] = o;
}

extern "C" void kernel_launch(void* const* d_in, const int* in_sizes, int n_in,
                              void* d_out, int out_size, void* d_ws, size_t ws_size,
                              hipStream_t stream) {
  // d_in[0] = t (unused), d_in[1] = x f32 [8192][64], d_in[2] = A f32 [8192][8192]
  const float* x = (const float*)d_in[1];
  const float* A = (const float*)d_in[2];
  float* out = (float*)d_out;

  unsigned short* xb = (unsigned short*)d_ws;                  // 1 MB bf16 x
  float* spart = (float*)((char*)d_ws + (size_t)N * DIM * 2);  // 256 KB partials

  cvt_kernel<<<512, 256, 0, stream>>>(x, xb);
  main_kernel<<<1024, 256, 0, stream>>>(A, xb, spart);
  finish_kernel<<<512, 256, 0, stream>>>(x, spart, out);
}